// Round 14
// baseline (813.248 us; speedup 1.0000x reference)
//
#include <hip/hip_runtime.h>
#include <hip/hip_bf16.h>
#include <stdint.h>

#define T_TOK 8192
#define D_DIM 1024
#define E_NUM 8
#define H_DIM 4096
#define NPAD 144          // padded panel count, multiple of 8 (max panels = 135)
#define PPX (NPAD / 8)    // panels per XCD chunk = 18
#define GATEB 2048        // gate blocks (4 tokens each)
#define TRB 4096          // transpose blocks (256x64 src tile each)

typedef short bf16x8 __attribute__((ext_vector_type(8)));
typedef float f32x4 __attribute__((ext_vector_type(4)));
typedef unsigned short usv8 __attribute__((ext_vector_type(8)));

#define AS1 __attribute__((address_space(1)))
#define AS3 __attribute__((address_space(3)))

__device__ __forceinline__ unsigned short f2b(float f) {
  union { float f; uint32_t u; } v; v.f = f;
  uint32_t r = (v.u + 0x7fffu + ((v.u >> 16) & 1u)) >> 16;
  return (unsigned short)r;
}

__device__ __forceinline__ float gelu_tanh(float x) {
  float u = 0.7978845608028654f * (x + 0.044715f * x * x * x);
  u = fminf(fmaxf(u, -15.f), 15.f);
  float e = __expf(2.f * u);
  float t = (e - 1.f) / (e + 1.f);
  return 0.5f * x * (1.f + t);
}

__device__ __forceinline__ void gload_lds16(const void* g, void* l) {
  __builtin_amdgcn_global_load_lds((const AS1 uint32_t*)g, (AS3 uint32_t*)l, 16, 0, 0);
}

// ---------------- fused prep: gate (+x->bf16 +out bias-init) THEN weight transposes -------
// blocks [0, GATEB): gate 4 tokens each; blocks [GATEB, GATEB+TRB): LDS-free transpose.
__global__ __launch_bounds__(256) void moe_prep(const float* __restrict__ x,
                                                const float* __restrict__ gw,
                                                const float* __restrict__ gb,
                                                const float* __restrict__ w1,
                                                const float* __restrict__ w2,
                                                const float* __restrict__ b2,
                                                unsigned short* __restrict__ xb,
                                                unsigned short* __restrict__ w1t,
                                                unsigned short* __restrict__ w2t,
                                                int2* __restrict__ sel,
                                                float2* __restrict__ wts,
                                                int* __restrict__ meta,
                                                float* __restrict__ out) {
  int z = blockIdx.x;
  if (z >= GATEB) {
    // ------- in-register 8x8 transpose+convert, no LDS -------
    int z2 = z - GATEB;            // 0..4095
    int e = (z2 >> 8) & 7;
    int bx = z2 & 255;
    const float* in; unsigned short* outp; int R, C, ry, cy;
    if (z2 < TRB / 2) { in = w1 + (size_t)e * D_DIM * H_DIM; outp = w1t + (size_t)e * D_DIM * H_DIM;
                        R = D_DIM; C = H_DIM; ry = bx >> 6; cy = bx & 63; }
    else              { in = w2 + (size_t)e * H_DIM * D_DIM; outp = w2t + (size_t)e * H_DIM * D_DIM;
                        R = H_DIM; C = D_DIM; ry = bx >> 4; cy = bx & 15; }
    int r0 = ry * 256, c0 = cy * 64;
    int t = threadIdx.x, rg = t >> 3, cg = t & 7;
    const float* src = in + (size_t)(r0 + rg * 8) * C + c0 + cg * 8;
    float4 va[8], vb[8];
#pragma unroll
    for (int rr = 0; rr < 8; ++rr) {
      va[rr] = *(const float4*)(src + (size_t)rr * C);
      vb[rr] = *(const float4*)(src + (size_t)rr * C + 4);
    }
    unsigned short* dst = outp + (size_t)(c0 + cg * 8) * R + r0 + rg * 8;
#pragma unroll
    for (int cc = 0; cc < 8; ++cc) {
      usv8 o;
#pragma unroll
      for (int rr = 0; rr < 8; ++rr) {
        float f = (cc < 4) ? ((const float*)&va[rr])[cc] : ((const float*)&vb[rr])[cc - 4];
        o[rr] = f2b(f);
      }
      *(usv8*)(dst + (size_t)cc * R) = o;
    }
    return;
  }
  // ------- gate + convert + out bias-init -------
  int lane = threadIdx.x & 63;
  int t = z * 4 + (threadIdx.x >> 6);
  const float* xr = x + (size_t)t * D_DIM;
  unsigned short* xo = xb + (size_t)t * D_DIM;
  float acc[8];
#pragma unroll
  for (int e = 0; e < 8; e++) acc[e] = 0.f;
#pragma unroll
  for (int i = 0; i < 4; i++) {
    int d0 = lane * 4 + i * 256;
    float4 xv = *(const float4*)(xr + d0);
    ushort4 o;
    o.x = f2b(xv.x); o.y = f2b(xv.y); o.z = f2b(xv.z); o.w = f2b(xv.w);
    *(ushort4*)(xo + d0) = o;
    const float* gp = gw + (size_t)d0 * 8;
    float xs[4] = {xv.x, xv.y, xv.z, xv.w};
#pragma unroll
    for (int j = 0; j < 4; j++) {
#pragma unroll
      for (int e = 0; e < 8; e++) acc[e] += xs[j] * gp[j * 8 + e];
    }
  }
#pragma unroll
  for (int off = 32; off > 0; off >>= 1) {
#pragma unroll
    for (int e = 0; e < 8; e++) acc[e] += __shfl_xor(acc[e], off);
  }
  // butterfly leaves full sums in every lane: all lanes compute top-2 redundantly
  float lg[8];
#pragma unroll
  for (int e = 0; e < 8; e++) lg[e] = acc[e] + gb[e];
  int e0 = 0; float b0v = lg[0];
#pragma unroll
  for (int e = 1; e < 8; e++) if (lg[e] > b0v) { b0v = lg[e]; e0 = e; }
  int e1 = -1; float b1v = -1e30f;
#pragma unroll
  for (int e = 0; e < 8; e++) if (e != e0 && lg[e] > b1v) { b1v = lg[e]; e1 = e; }
  float d = __expf(b1v - b0v);
  float w0 = 1.f / (1.f + d), w1v = d / (1.f + d);
  if (lane == 0) {
    sel[t] = make_int2(e0, e1);
    wts[t] = make_float2(w0, w1v);
    atomicAdd(&meta[e0], 1);
    atomicAdd(&meta[e1], 1);
  }
  // out[t] = w0*b2[e0] + w1*b2[e1]
  const float* ba = b2 + (size_t)e0 * D_DIM;
  const float* bb = b2 + (size_t)e1 * D_DIM;
  float* orow = out + (size_t)t * D_DIM;
#pragma unroll
  for (int k = 0; k < 4; k++) {
    int dd = lane * 4 + k * 256;
    float4 a = *(const float4*)(ba + dd);
    float4 b = *(const float4*)(bb + dd);
    float4 o;
    o.x = w0 * a.x + w1v * b.x;
    o.y = w0 * a.y + w1v * b.y;
    o.z = w0 * a.z + w1v * b.z;
    o.w = w0 * a.w + w1v * b.w;
    *(float4*)(orow + dd) = o;
  }
}

// ---------------- scatter (inline prefix from counts; cursors start at 0) ----------------
__global__ __launch_bounds__(256) void moe_scatter(const int2* __restrict__ sel,
                                                   const float2* __restrict__ wts,
                                                   int* __restrict__ meta,
                                                   int* __restrict__ token_id,
                                                   float* __restrict__ weightv) {
  int t = blockIdx.x * 256 + threadIdx.x;
  if (t >= T_TOK) return;
  int cnt[8];
#pragma unroll
  for (int e = 0; e < 8; e++) cnt[e] = meta[e];
  int2 s = sel[t];
  float2 w = wts[t];
  int o0 = 0, o1 = 0;
#pragma unroll
  for (int e = 0; e < 8; e++) {
    if (e < s.x) o0 += cnt[e];
    if (e < s.y) o1 += cnt[e];
  }
  int p0 = o0 + atomicAdd(&meta[20 + s.x], 1); token_id[p0] = t; weightv[p0] = w.x;
  int p1 = o1 + atomicAdd(&meta[20 + s.y], 1); token_id[p1] = t; weightv[p1] = w.y;
}

// Panel decode from counts: panel slot wi -> (expert e, m0, seg, ne); invalid -> e=-1.
__device__ __forceinline__ bool panel_decode(const int* __restrict__ meta, int wi,
                                             int& e, int& m0, int& seg, int& ne) {
  int acc = 0, pre = 0;
  e = -1;
#pragma unroll
  for (int k = 0; k < 8; k++) {
    int ck = meta[k];
    int nb = (ck + 127) >> 7;
    if (wi >= acc && wi < acc + nb) { e = k; m0 = (wi - acc) << 7; seg = pre; ne = ck; }
    acc += nb; pre += ck;
  }
  return e >= 0;
}

// Bank-conflict s-XOR swizzle (r12, conflicts==0): phys s = log s ^ ((row>>1)&3).

// ---------------- GEMM1: h = gelu(x@w1+b1), BK=32 2-phase, swizzled ----------------
__global__ __launch_bounds__(256, 4) void moe_gemm1(const unsigned short* __restrict__ xb,
                                                    const unsigned short* __restrict__ w1t,
                                                    const float* __restrict__ b1,
                                                    const int* __restrict__ meta,
                                                    const int* __restrict__ token_id,
                                                    unsigned short* __restrict__ hbuf) {
  int b = blockIdx.x;
  int c = b & 7, u = b >> 3;
  int n = u & 31, ps = u >> 5;           // NB = 32
  int e, m0, seg, ne;
  if (!panel_decode(meta, c * PPX + ps, e, m0, seg, ne)) return;
  int n0 = n * 128;
  const unsigned short* wB = w1t + (size_t)e * H_DIM * D_DIM;

  __shared__ unsigned short As[2][4096];
  __shared__ unsigned short Bs[2][4096];

  int tid = threadIdx.x, lane = tid & 63, wv = tid >> 6;
  const unsigned short* aptr[2];
  const unsigned short* bptr[2];
#pragma unroll
  for (int q = 0; q < 2; q++) {
    int chunk = tid + q * 256;
    int row = chunk >> 2;
    int ko = ((chunk & 3) ^ ((chunk >> 3) & 3)) * 8;   // logical s for this physical slot
    int gi = m0 + row; if (gi >= ne) gi = m0;
    int tok = token_id[seg + gi];
    aptr[q] = xb + (size_t)tok * D_DIM + ko;
    bptr[q] = wB + (size_t)(n0 + row) * D_DIM + ko;
  }
  auto stage = [&](int buf, int kt) {
#pragma unroll
    for (int q = 0; q < 2; q++) {
      gload_lds16(aptr[q] + kt * 32, &As[buf][(wv + 4 * q) * 512]);
      gload_lds16(bptr[q] + kt * 32, &Bs[buf][(wv + 4 * q) * 512]);
    }
  };

  f32x4 acc[4][4] = {};
  int wr = wv >> 1, wc = wv & 1;
  int sswz = ((lane >> 4) ^ ((lane >> 1) & 3)) * 8;    // swizzled k-seg, per-lane const
  int abase = (wr * 64 + (lane & 15)) * 32 + sswz;
  int bbase = (wc * 64 + (lane & 15)) * 32 + sswz;

  stage(0, 0);
  __syncthreads();
  const int nk = D_DIM / 32;
  for (int kt = 0; kt < nk; ++kt) {
    int cur = kt & 1;
    if (kt + 1 < nk) stage(cur ^ 1, kt + 1);
    bf16x8 af[4], bfr[4];
#pragma unroll
    for (int m = 0; m < 4; m++) af[m] = *(const bf16x8*)&As[cur][abase + m * 512];
#pragma unroll
    for (int nn = 0; nn < 4; nn++) bfr[nn] = *(const bf16x8*)&Bs[cur][bbase + nn * 512];
#pragma unroll
    for (int m = 0; m < 4; m++)
#pragma unroll
      for (int nn = 0; nn < 4; nn++)
        acc[m][nn] = __builtin_amdgcn_mfma_f32_16x16x32_bf16(af[m], bfr[nn], acc[m][nn], 0, 0, 0);
    __syncthreads();
  }

  int rbase = wr * 64 + (lane >> 4) * 4;
  int cbase = n0 + wc * 64 + (lane & 15);
  const float* b1e = b1 + (size_t)e * H_DIM + cbase;
  float bv[4];
#pragma unroll
  for (int nn = 0; nn < 4; nn++) bv[nn] = b1e[nn * 16];
#pragma unroll
  for (int m = 0; m < 4; m++) {
#pragma unroll
    for (int j = 0; j < 4; j++) {
      int gi = m0 + rbase + m * 16 + j;
      if (gi < ne) {
        unsigned short* hrow = hbuf + (size_t)(seg + gi) * H_DIM + cbase;
#pragma unroll
        for (int nn = 0; nn < 4; nn++) {
          float v = acc[m][nn][j] + bv[nn];
          hrow[nn * 16] = f2b(gelu_tanh(v));
        }
      }
    }
  }
}

// ---------------- GEMM2: BK=32 2-phase + split-K=2, swizzled, bias via prep init ----------
__global__ __launch_bounds__(256, 4) void moe_gemm2(const unsigned short* __restrict__ hbuf,
                                                    const unsigned short* __restrict__ w2t,
                                                    const int* __restrict__ meta,
                                                    const int* __restrict__ token_id,
                                                    const float* __restrict__ weightv,
                                                    float* __restrict__ out) {
  int b = blockIdx.x;
  int c = b & 7, u = b >> 3;
  int n = u & 7, ks = (u >> 3) & 1, ps = u >> 4;   // NB = 8, KS = 2
  int e, m0, seg, ne;
  if (!panel_decode(meta, c * PPX + ps, e, m0, seg, ne)) return;
  int n0 = n * 128;
  int kbase = ks * 2048;
  const unsigned short* wB = w2t + (size_t)e * D_DIM * H_DIM;

  __shared__ unsigned short As[2][4096];
  __shared__ unsigned short Bs[2][4096];

  int tid = threadIdx.x, lane = tid & 63, wv = tid >> 6;
  const unsigned short* aptr[2];
  const unsigned short* bptr[2];
#pragma unroll
  for (int q = 0; q < 2; q++) {
    int chunk = tid + q * 256;
    int row = chunk >> 2;
    int ko = ((chunk & 3) ^ ((chunk >> 3) & 3)) * 8;
    int gi = m0 + row; if (gi >= ne) gi = m0;
    aptr[q] = hbuf + (size_t)(seg + gi) * H_DIM + kbase + ko;
    bptr[q] = wB + (size_t)(n0 + row) * H_DIM + kbase + ko;
  }
  auto stage = [&](int buf, int kt) {
#pragma unroll
    for (int q = 0; q < 2; q++) {
      gload_lds16(aptr[q] + kt * 32, &As[buf][(wv + 4 * q) * 512]);
      gload_lds16(bptr[q] + kt * 32, &Bs[buf][(wv + 4 * q) * 512]);
    }
  };

  f32x4 acc[4][4] = {};
  int wr = wv >> 1, wc = wv & 1;
  int sswz = ((lane >> 4) ^ ((lane >> 1) & 3)) * 8;
  int abase = (wr * 64 + (lane & 15)) * 32 + sswz;
  int bbase = (wc * 64 + (lane & 15)) * 32 + sswz;

  stage(0, 0);
  __syncthreads();
  const int nk = 2048 / 32;   // 64 K-tiles per half
  for (int kt = 0; kt < nk; ++kt) {
    int cur = kt & 1;
    if (kt + 1 < nk) stage(cur ^ 1, kt + 1);
    bf16x8 af[4], bfr[4];
#pragma unroll
    for (int m = 0; m < 4; m++) af[m] = *(const bf16x8*)&As[cur][abase + m * 512];
#pragma unroll
    for (int nn = 0; nn < 4; nn++) bfr[nn] = *(const bf16x8*)&Bs[cur][bbase + nn * 512];
#pragma unroll
    for (int m = 0; m < 4; m++)
#pragma unroll
      for (int nn = 0; nn < 4; nn++)
        acc[m][nn] = __builtin_amdgcn_mfma_f32_16x16x32_bf16(af[m], bfr[nn], acc[m][nn], 0, 0, 0);
    __syncthreads();
  }

  int rbase = wr * 64 + (lane >> 4) * 4;
  int cbase = n0 + wc * 64 + (lane & 15);
#pragma unroll
  for (int m = 0; m < 4; m++) {
#pragma unroll
    for (int j = 0; j < 4; j++) {
      int gi = m0 + rbase + m * 16 + j;
      if (gi < ne) {
        int p = seg + gi;
        int tok = token_id[p];
        float wt = weightv[p];
        float* orow = out + (size_t)tok * D_DIM + cbase;
#pragma unroll
        for (int nn = 0; nn < 4; nn++)
          atomicAdd(&orow[nn * 16], wt * acc[m][nn][j]);
      }
    }
  }
}

extern "C" void kernel_launch(void* const* d_in, const int* in_sizes, int n_in,
                              void* d_out, int out_size, void* d_ws, size_t ws_size,
                              hipStream_t stream) {
  const float* x      = (const float*)d_in[0];
  const float* gate_w = (const float*)d_in[1];
  const float* gate_b = (const float*)d_in[2];
  const float* w1     = (const float*)d_in[3];
  const float* b1     = (const float*)d_in[4];
  const float* w2     = (const float*)d_in[5];
  const float* b2     = (const float*)d_in[6];
  float* out = (float*)d_out;

  uint8_t* ws = (uint8_t*)d_ws;
  unsigned short* hbuf = (unsigned short*)(ws);                 // 128 MiB
  unsigned short* xb   = (unsigned short*)(ws + 134217728ull);  // 16 MiB
  unsigned short* w1t  = (unsigned short*)(ws + 150994944ull);  // 64 MiB
  unsigned short* w2t  = (unsigned short*)(ws + 218103808ull);  // 64 MiB
  int*    token_id = (int*)  (ws + 285212672ull);               // 64 KiB
  float*  weightv  = (float*)(ws + 285278208ull);               // 64 KiB
  float2* wts      = (float2*)(ws + 285343744ull);              // 64 KiB
  int2*   sel      = (int2*) (ws + 285409280ull);               // 64 KiB
  int*    meta     = (int*)  (ws + 285474816ull);               // 512 B

  hipMemsetAsync(meta, 0, 128, stream);

  moe_prep<<<dim3(GATEB + TRB), 256, 0, stream>>>(
      x, gate_w, gate_b, w1, w2, b2, xb, w1t, w2t, sel, wts, meta, out);
  moe_scatter<<<dim3(T_TOK / 256), 256, 0, stream>>>(sel, wts, meta, token_id, weightv);

  moe_gemm1<<<dim3(NPAD * 32), 256, 0, stream>>>(xb, w1t, b1, meta, token_id, hbuf);
  moe_gemm2<<<dim3(NPAD * 16), 256, 0, stream>>>(hbuf, w2t, meta, token_id, weightv, out);
}

// Round 15
// 795.908 us; speedup vs baseline: 1.0218x; 1.0218x over previous
//
#include <hip/hip_runtime.h>
#include <hip/hip_bf16.h>
#include <stdint.h>

#define T_TOK 8192
#define D_DIM 1024
#define E_NUM 8
#define H_DIM 4096
#define NPAD 144          // padded panel count, multiple of 8 (max panels = 135)
#define PPX (NPAD / 8)    // panels per XCD chunk = 18
#define GATEB 2048        // gate blocks (4 tokens each)
#define TRB 4096          // transpose blocks (256x64 src tile each)

typedef short bf16x8 __attribute__((ext_vector_type(8)));
typedef float f32x4 __attribute__((ext_vector_type(4)));
typedef unsigned short usv8 __attribute__((ext_vector_type(8)));

#define AS1 __attribute__((address_space(1)))
#define AS3 __attribute__((address_space(3)))

__device__ __forceinline__ unsigned short f2b(float f) {
  union { float f; uint32_t u; } v; v.f = f;
  uint32_t r = (v.u + 0x7fffu + ((v.u >> 16) & 1u)) >> 16;
  return (unsigned short)r;
}

__device__ __forceinline__ float gelu_tanh(float x) {
  float u = 0.7978845608028654f * (x + 0.044715f * x * x * x);
  u = fminf(fmaxf(u, -15.f), 15.f);
  float e = __expf(2.f * u);
  float t = (e - 1.f) / (e + 1.f);
  return 0.5f * x * (1.f + t);
}

__device__ __forceinline__ void gload_lds16(const void* g, void* l) {
  __builtin_amdgcn_global_load_lds((const AS1 uint32_t*)g, (AS3 uint32_t*)l, 16, 0, 0);
}

// ---------------- fused prep: gate (+x->bf16 +out bias-init) + weight transposes ----------
// blocks [0, GATEB): gate 4 tokens each;
// blocks [GATEB, GATEB+TRB): 256x64 transpose with 512B-coalesced writes via LDS.
__global__ __launch_bounds__(256) void moe_prep(const float* __restrict__ x,
                                                const float* __restrict__ gw,
                                                const float* __restrict__ gb,
                                                const float* __restrict__ w1,
                                                const float* __restrict__ w2,
                                                const float* __restrict__ b2,
                                                unsigned short* __restrict__ xb,
                                                unsigned short* __restrict__ w1t,
                                                unsigned short* __restrict__ w2t,
                                                int2* __restrict__ sel,
                                                float2* __restrict__ wts,
                                                int* __restrict__ meta,
                                                float* __restrict__ out) {
  __shared__ unsigned short tile[64][260];   // [src col][src row] bf16, 33.3 KiB
  int z = blockIdx.x;
  if (z >= GATEB) {
    // ------- transpose+convert: 256 src rows x 64 src cols -------
    int z2 = z - GATEB;            // 0..4095
    int e = (z2 >> 8) & 7;
    int bx = z2 & 255;
    const float* in; unsigned short* outp; int R, C, ry, cy;
    if (z2 < TRB / 2) { in = w1 + (size_t)e * D_DIM * H_DIM; outp = w1t + (size_t)e * D_DIM * H_DIM;
                        R = D_DIM; C = H_DIM; ry = bx >> 6; cy = bx & 63; }
    else              { in = w2 + (size_t)e * H_DIM * D_DIM; outp = w2t + (size_t)e * H_DIM * D_DIM;
                        R = H_DIM; C = D_DIM; ry = bx >> 4; cy = bx & 15; }
    int r0 = ry * 256, c0 = cy * 64;
    int t = threadIdx.x;
    // phase 1: read 4x(4 rows x 16B) coalesced, convert, transposed 8B LDS writes
    int sc = (t & 15) * 4;          // col quad
    int srb = (t >> 4) * 4;         // row quad base (0..60)
#pragma unroll
    for (int it = 0; it < 4; ++it) {
      int sr = srb + it * 64;
      float4 v0 = *(const float4*)(in + (size_t)(r0 + sr + 0) * C + c0 + sc);
      float4 v1 = *(const float4*)(in + (size_t)(r0 + sr + 1) * C + c0 + sc);
      float4 v2 = *(const float4*)(in + (size_t)(r0 + sr + 2) * C + c0 + sc);
      float4 v3 = *(const float4*)(in + (size_t)(r0 + sr + 3) * C + c0 + sc);
      ushort4 o;
      o.x = f2b(v0.x); o.y = f2b(v1.x); o.z = f2b(v2.x); o.w = f2b(v3.x);
      *(ushort4*)&tile[sc + 0][sr] = o;
      o.x = f2b(v0.y); o.y = f2b(v1.y); o.z = f2b(v2.y); o.w = f2b(v3.y);
      *(ushort4*)&tile[sc + 1][sr] = o;
      o.x = f2b(v0.z); o.y = f2b(v1.z); o.z = f2b(v2.z); o.w = f2b(v3.z);
      *(ushort4*)&tile[sc + 2][sr] = o;
      o.x = f2b(v0.w); o.y = f2b(v1.w); o.z = f2b(v2.w); o.w = f2b(v3.w);
      *(ushort4*)&tile[sc + 3][sr] = o;
    }
    __syncthreads();
    // phase 2: half-wave per output row -> 512B contiguous global stores
    int wv = t >> 6, lane = t & 63;
    int rowHalf = lane >> 5, el = (lane & 31) * 8;
#pragma unroll
    for (int it = 0; it < 8; ++it) {
      int orow = wv * 16 + it * 2 + rowHalf;   // 0..63
      usv8 o = *(const usv8*)&tile[orow][el];
      *(usv8*)(outp + (size_t)(c0 + orow) * R + r0 + el) = o;
    }
    return;
  }
  // ------- gate + convert + out bias-init -------
  int lane = threadIdx.x & 63;
  int t = z * 4 + (threadIdx.x >> 6);
  const float* xr = x + (size_t)t * D_DIM;
  unsigned short* xo = xb + (size_t)t * D_DIM;
  float acc[8];
#pragma unroll
  for (int e = 0; e < 8; e++) acc[e] = 0.f;
#pragma unroll
  for (int i = 0; i < 4; i++) {
    int d0 = lane * 4 + i * 256;
    float4 xv = *(const float4*)(xr + d0);
    ushort4 o;
    o.x = f2b(xv.x); o.y = f2b(xv.y); o.z = f2b(xv.z); o.w = f2b(xv.w);
    *(ushort4*)(xo + d0) = o;
    const float* gp = gw + (size_t)d0 * 8;
    float xs[4] = {xv.x, xv.y, xv.z, xv.w};
#pragma unroll
    for (int j = 0; j < 4; j++) {
#pragma unroll
      for (int e = 0; e < 8; e++) acc[e] += xs[j] * gp[j * 8 + e];
    }
  }
#pragma unroll
  for (int off = 32; off > 0; off >>= 1) {
#pragma unroll
    for (int e = 0; e < 8; e++) acc[e] += __shfl_xor(acc[e], off);
  }
  float lg[8];
#pragma unroll
  for (int e = 0; e < 8; e++) lg[e] = acc[e] + gb[e];
  int e0 = 0; float b0v = lg[0];
#pragma unroll
  for (int e = 1; e < 8; e++) if (lg[e] > b0v) { b0v = lg[e]; e0 = e; }
  int e1 = -1; float b1v = -1e30f;
#pragma unroll
  for (int e = 0; e < 8; e++) if (e != e0 && lg[e] > b1v) { b1v = lg[e]; e1 = e; }
  float d = __expf(b1v - b0v);
  float w0 = 1.f / (1.f + d), w1v = d / (1.f + d);
  if (lane == 0) {
    sel[t] = make_int2(e0, e1);
    wts[t] = make_float2(w0, w1v);
    atomicAdd(&meta[e0], 1);
    atomicAdd(&meta[e1], 1);
  }
  const float* ba = b2 + (size_t)e0 * D_DIM;
  const float* bb = b2 + (size_t)e1 * D_DIM;
  float* orow = out + (size_t)t * D_DIM;
#pragma unroll
  for (int k = 0; k < 4; k++) {
    int dd = lane * 4 + k * 256;
    float4 a = *(const float4*)(ba + dd);
    float4 b = *(const float4*)(bb + dd);
    float4 o;
    o.x = w0 * a.x + w1v * b.x;
    o.y = w0 * a.y + w1v * b.y;
    o.z = w0 * a.z + w1v * b.z;
    o.w = w0 * a.w + w1v * b.w;
    *(float4*)(orow + dd) = o;
  }
}

// ---------------- scatter (inline prefix from counts; cursors start at 0) ----------------
__global__ __launch_bounds__(256) void moe_scatter(const int2* __restrict__ sel,
                                                   const float2* __restrict__ wts,
                                                   int* __restrict__ meta,
                                                   int* __restrict__ token_id,
                                                   float* __restrict__ weightv) {
  int t = blockIdx.x * 256 + threadIdx.x;
  if (t >= T_TOK) return;
  int cnt[8];
#pragma unroll
  for (int e = 0; e < 8; e++) cnt[e] = meta[e];
  int2 s = sel[t];
  float2 w = wts[t];
  int o0 = 0, o1 = 0;
#pragma unroll
  for (int e = 0; e < 8; e++) {
    if (e < s.x) o0 += cnt[e];
    if (e < s.y) o1 += cnt[e];
  }
  int p0 = o0 + atomicAdd(&meta[20 + s.x], 1); token_id[p0] = t; weightv[p0] = w.x;
  int p1 = o1 + atomicAdd(&meta[20 + s.y], 1); token_id[p1] = t; weightv[p1] = w.y;
}

// Panel decode from counts: panel slot wi -> (expert e, m0, seg, ne); invalid -> e=-1.
__device__ __forceinline__ bool panel_decode(const int* __restrict__ meta, int wi,
                                             int& e, int& m0, int& seg, int& ne) {
  int acc = 0, pre = 0;
  e = -1;
#pragma unroll
  for (int k = 0; k < 8; k++) {
    int ck = meta[k];
    int nb = (ck + 127) >> 7;
    if (wi >= acc && wi < acc + nb) { e = k; m0 = (wi - acc) << 7; seg = pre; ne = ck; }
    acc += nb; pre += ck;
  }
  return e >= 0;
}

// Bank-conflict s-XOR swizzle (r12, conflicts==0): phys s = log s ^ ((row>>1)&3).

// ---------------- GEMM1: h = gelu(x@w1+b1), BK=32 2-phase, swizzled ----------------
__global__ __launch_bounds__(256, 4) void moe_gemm1(const unsigned short* __restrict__ xb,
                                                    const unsigned short* __restrict__ w1t,
                                                    const float* __restrict__ b1,
                                                    const int* __restrict__ meta,
                                                    const int* __restrict__ token_id,
                                                    unsigned short* __restrict__ hbuf) {
  int b = blockIdx.x;
  int c = b & 7, u = b >> 3;
  int n = u & 31, ps = u >> 5;           // NB = 32
  int e, m0, seg, ne;
  if (!panel_decode(meta, c * PPX + ps, e, m0, seg, ne)) return;
  int n0 = n * 128;
  const unsigned short* wB = w1t + (size_t)e * H_DIM * D_DIM;

  __shared__ unsigned short As[2][4096];
  __shared__ unsigned short Bs[2][4096];

  int tid = threadIdx.x, lane = tid & 63, wv = tid >> 6;
  const unsigned short* aptr[2];
  const unsigned short* bptr[2];
#pragma unroll
  for (int q = 0; q < 2; q++) {
    int chunk = tid + q * 256;
    int row = chunk >> 2;
    int ko = ((chunk & 3) ^ ((chunk >> 3) & 3)) * 8;   // logical s for this physical slot
    int gi = m0 + row; if (gi >= ne) gi = m0;
    int tok = token_id[seg + gi];
    aptr[q] = xb + (size_t)tok * D_DIM + ko;
    bptr[q] = wB + (size_t)(n0 + row) * D_DIM + ko;
  }
  auto stage = [&](int buf, int kt) {
#pragma unroll
    for (int q = 0; q < 2; q++) {
      gload_lds16(aptr[q] + kt * 32, &As[buf][(wv + 4 * q) * 512]);
      gload_lds16(bptr[q] + kt * 32, &Bs[buf][(wv + 4 * q) * 512]);
    }
  };

  f32x4 acc[4][4] = {};
  int wr = wv >> 1, wc = wv & 1;
  int sswz = ((lane >> 4) ^ ((lane >> 1) & 3)) * 8;    // swizzled k-seg, per-lane const
  int abase = (wr * 64 + (lane & 15)) * 32 + sswz;
  int bbase = (wc * 64 + (lane & 15)) * 32 + sswz;

  stage(0, 0);
  __syncthreads();
  const int nk = D_DIM / 32;
  for (int kt = 0; kt < nk; ++kt) {
    int cur = kt & 1;
    if (kt + 1 < nk) stage(cur ^ 1, kt + 1);
    bf16x8 af[4], bfr[4];
#pragma unroll
    for (int m = 0; m < 4; m++) af[m] = *(const bf16x8*)&As[cur][abase + m * 512];
#pragma unroll
    for (int nn = 0; nn < 4; nn++) bfr[nn] = *(const bf16x8*)&Bs[cur][bbase + nn * 512];
#pragma unroll
    for (int m = 0; m < 4; m++)
#pragma unroll
      for (int nn = 0; nn < 4; nn++)
        acc[m][nn] = __builtin_amdgcn_mfma_f32_16x16x32_bf16(af[m], bfr[nn], acc[m][nn], 0, 0, 0);
    __syncthreads();
  }

  int rbase = wr * 64 + (lane >> 4) * 4;
  int cbase = n0 + wc * 64 + (lane & 15);
  const float* b1e = b1 + (size_t)e * H_DIM + cbase;
  float bv[4];
#pragma unroll
  for (int nn = 0; nn < 4; nn++) bv[nn] = b1e[nn * 16];
#pragma unroll
  for (int m = 0; m < 4; m++) {
#pragma unroll
    for (int j = 0; j < 4; j++) {
      int gi = m0 + rbase + m * 16 + j;
      if (gi < ne) {
        unsigned short* hrow = hbuf + (size_t)(seg + gi) * H_DIM + cbase;
#pragma unroll
        for (int nn = 0; nn < 4; nn++) {
          float v = acc[m][nn][j] + bv[nn];
          hrow[nn * 16] = f2b(gelu_tanh(v));
        }
      }
    }
  }
}

// ---------------- GEMM2: BK=32 2-phase + split-K=2, swizzled, bias via prep init ----------
__global__ __launch_bounds__(256, 4) void moe_gemm2(const unsigned short* __restrict__ hbuf,
                                                    const unsigned short* __restrict__ w2t,
                                                    const int* __restrict__ meta,
                                                    const int* __restrict__ token_id,
                                                    const float* __restrict__ weightv,
                                                    float* __restrict__ out) {
  int b = blockIdx.x;
  int c = b & 7, u = b >> 3;
  int n = u & 7, ks = (u >> 3) & 1, ps = u >> 4;   // NB = 8, KS = 2
  int e, m0, seg, ne;
  if (!panel_decode(meta, c * PPX + ps, e, m0, seg, ne)) return;
  int n0 = n * 128;
  int kbase = ks * 2048;
  const unsigned short* wB = w2t + (size_t)e * D_DIM * H_DIM;

  __shared__ unsigned short As[2][4096];
  __shared__ unsigned short Bs[2][4096];

  int tid = threadIdx.x, lane = tid & 63, wv = tid >> 6;
  const unsigned short* aptr[2];
  const unsigned short* bptr[2];
#pragma unroll
  for (int q = 0; q < 2; q++) {
    int chunk = tid + q * 256;
    int row = chunk >> 2;
    int ko = ((chunk & 3) ^ ((chunk >> 3) & 3)) * 8;
    int gi = m0 + row; if (gi >= ne) gi = m0;
    aptr[q] = hbuf + (size_t)(seg + gi) * H_DIM + kbase + ko;
    bptr[q] = wB + (size_t)(n0 + row) * H_DIM + kbase + ko;
  }
  auto stage = [&](int buf, int kt) {
#pragma unroll
    for (int q = 0; q < 2; q++) {
      gload_lds16(aptr[q] + kt * 32, &As[buf][(wv + 4 * q) * 512]);
      gload_lds16(bptr[q] + kt * 32, &Bs[buf][(wv + 4 * q) * 512]);
    }
  };

  f32x4 acc[4][4] = {};
  int wr = wv >> 1, wc = wv & 1;
  int sswz = ((lane >> 4) ^ ((lane >> 1) & 3)) * 8;
  int abase = (wr * 64 + (lane & 15)) * 32 + sswz;
  int bbase = (wc * 64 + (lane & 15)) * 32 + sswz;

  stage(0, 0);
  __syncthreads();
  const int nk = 2048 / 32;   // 64 K-tiles per half
  for (int kt = 0; kt < nk; ++kt) {
    int cur = kt & 1;
    if (kt + 1 < nk) stage(cur ^ 1, kt + 1);
    bf16x8 af[4], bfr[4];
#pragma unroll
    for (int m = 0; m < 4; m++) af[m] = *(const bf16x8*)&As[cur][abase + m * 512];
#pragma unroll
    for (int nn = 0; nn < 4; nn++) bfr[nn] = *(const bf16x8*)&Bs[cur][bbase + nn * 512];
#pragma unroll
    for (int m = 0; m < 4; m++)
#pragma unroll
      for (int nn = 0; nn < 4; nn++)
        acc[m][nn] = __builtin_amdgcn_mfma_f32_16x16x32_bf16(af[m], bfr[nn], acc[m][nn], 0, 0, 0);
    __syncthreads();
  }

  int rbase = wr * 64 + (lane >> 4) * 4;
  int cbase = n0 + wc * 64 + (lane & 15);
#pragma unroll
  for (int m = 0; m < 4; m++) {
#pragma unroll
    for (int j = 0; j < 4; j++) {
      int gi = m0 + rbase + m * 16 + j;
      if (gi < ne) {
        int p = seg + gi;
        int tok = token_id[p];
        float wt = weightv[p];
        float* orow = out + (size_t)tok * D_DIM + cbase;
#pragma unroll
        for (int nn = 0; nn < 4; nn++)
          atomicAdd(&orow[nn * 16], wt * acc[m][nn][j]);
      }
    }
  }
}

extern "C" void kernel_launch(void* const* d_in, const int* in_sizes, int n_in,
                              void* d_out, int out_size, void* d_ws, size_t ws_size,
                              hipStream_t stream) {
  const float* x      = (const float*)d_in[0];
  const float* gate_w = (const float*)d_in[1];
  const float* gate_b = (const float*)d_in[2];
  const float* w1     = (const float*)d_in[3];
  const float* b1     = (const float*)d_in[4];
  const float* w2     = (const float*)d_in[5];
  const float* b2     = (const float*)d_in[6];
  float* out = (float*)d_out;

  uint8_t* ws = (uint8_t*)d_ws;
  unsigned short* hbuf = (unsigned short*)(ws);                 // 128 MiB
  unsigned short* xb   = (unsigned short*)(ws + 134217728ull);  // 16 MiB
  unsigned short* w1t  = (unsigned short*)(ws + 150994944ull);  // 64 MiB
  unsigned short* w2t  = (unsigned short*)(ws + 218103808ull);  // 64 MiB
  int*    token_id = (int*)  (ws + 285212672ull);               // 64 KiB
  float*  weightv  = (float*)(ws + 285278208ull);               // 64 KiB
  float2* wts      = (float2*)(ws + 285343744ull);              // 64 KiB
  int2*   sel      = (int2*) (ws + 285409280ull);               // 64 KiB
  int*    meta     = (int*)  (ws + 285474816ull);               // 512 B

  hipMemsetAsync(meta, 0, 128, stream);

  moe_prep<<<dim3(GATEB + TRB), 256, 0, stream>>>(
      x, gate_w, gate_b, w1, w2, b2, xb, w1t, w2t, sel, wts, meta, out);
  moe_scatter<<<dim3(T_TOK / 256), 256, 0, stream>>>(sel, wts, meta, token_id, weightv);

  moe_gemm1<<<dim3(NPAD * 32), 256, 0, stream>>>(xb, w1t, b1, meta, token_id, hbuf);
  moe_gemm2<<<dim3(NPAD * 16), 256, 0, stream>>>(hbuf, w2t, meta, token_id, weightv, out);
}

// Round 16
// 793.283 us; speedup vs baseline: 1.0252x; 1.0033x over previous
//
#include <hip/hip_runtime.h>
#include <hip/hip_bf16.h>
#include <stdint.h>

#define T_TOK 8192
#define D_DIM 1024
#define E_NUM 8
#define H_DIM 4096
#define NPAD 144          // padded panel count, multiple of 8 (max panels = 135)
#define PPX (NPAD / 8)    // panels per XCD chunk = 18
#define GATEB 2048        // gate blocks (4 tokens each)
#define TRB1 2048         // w1 transpose blocks (in prep)
#define TRB2 2048         // w2 transpose blocks (in gemm1')

typedef short bf16x8 __attribute__((ext_vector_type(8)));
typedef float f32x4 __attribute__((ext_vector_type(4)));
typedef unsigned short usv8 __attribute__((ext_vector_type(8)));

#define AS1 __attribute__((address_space(1)))
#define AS3 __attribute__((address_space(3)))

__device__ __forceinline__ unsigned short f2b(float f) {
  union { float f; uint32_t u; } v; v.f = f;
  uint32_t r = (v.u + 0x7fffu + ((v.u >> 16) & 1u)) >> 16;
  return (unsigned short)r;
}

__device__ __forceinline__ float gelu_tanh(float x) {
  float u = 0.7978845608028654f * (x + 0.044715f * x * x * x);
  u = fminf(fmaxf(u, -15.f), 15.f);
  float e = __expf(2.f * u);
  float t = (e - 1.f) / (e + 1.f);
  return 0.5f * x * (1.f + t);
}

__device__ __forceinline__ void gload_lds16(const void* g, void* l) {
  __builtin_amdgcn_global_load_lds((const AS1 uint32_t*)g, (AS3 uint32_t*)l, 16, 0, 0);
}

// 256x64 fp32->bf16 transpose tile with 512B-coalesced writes via LDS (r15-verified).
// tile must point at [64][260] unsigned short LDS storage.
__device__ __forceinline__ void transpose_tile(const float* __restrict__ in,
                                               unsigned short* __restrict__ outp,
                                               int R, int C, int r0, int c0,
                                               unsigned short (*tile)[260], int t) {
  int sc = (t & 15) * 4;
  int srb = (t >> 4) * 4;
#pragma unroll
  for (int it = 0; it < 4; ++it) {
    int sr = srb + it * 64;
    float4 v0 = *(const float4*)(in + (size_t)(r0 + sr + 0) * C + c0 + sc);
    float4 v1 = *(const float4*)(in + (size_t)(r0 + sr + 1) * C + c0 + sc);
    float4 v2 = *(const float4*)(in + (size_t)(r0 + sr + 2) * C + c0 + sc);
    float4 v3 = *(const float4*)(in + (size_t)(r0 + sr + 3) * C + c0 + sc);
    ushort4 o;
    o.x = f2b(v0.x); o.y = f2b(v1.x); o.z = f2b(v2.x); o.w = f2b(v3.x);
    *(ushort4*)&tile[sc + 0][sr] = o;
    o.x = f2b(v0.y); o.y = f2b(v1.y); o.z = f2b(v2.y); o.w = f2b(v3.y);
    *(ushort4*)&tile[sc + 1][sr] = o;
    o.x = f2b(v0.z); o.y = f2b(v1.z); o.z = f2b(v2.z); o.w = f2b(v3.z);
    *(ushort4*)&tile[sc + 2][sr] = o;
    o.x = f2b(v0.w); o.y = f2b(v1.w); o.z = f2b(v2.w); o.w = f2b(v3.w);
    *(ushort4*)&tile[sc + 3][sr] = o;
  }
  __syncthreads();
  int wv = t >> 6, lane = t & 63;
  int rowHalf = lane >> 5, el = (lane & 31) * 8;
#pragma unroll
  for (int it = 0; it < 8; ++it) {
    int orow = wv * 16 + it * 2 + rowHalf;
    usv8 o = *(const usv8*)&tile[orow][el];
    *(usv8*)(outp + (size_t)(c0 + orow) * R + r0 + el) = o;
  }
}

// ---------------- prep: gate (+x->bf16 +out bias-init) + w1 transpose ----------------
__global__ __launch_bounds__(256) void moe_prep(const float* __restrict__ x,
                                                const float* __restrict__ gw,
                                                const float* __restrict__ gb,
                                                const float* __restrict__ w1,
                                                const float* __restrict__ b2,
                                                unsigned short* __restrict__ xb,
                                                unsigned short* __restrict__ w1t,
                                                int2* __restrict__ sel,
                                                float2* __restrict__ wts,
                                                int* __restrict__ meta,
                                                float* __restrict__ out) {
  __shared__ unsigned short tile[64][260];
  int z = blockIdx.x;
  if (z >= GATEB) {
    int z2 = z - GATEB;            // 0..2047: w1 [D][H] -> w1t [H][D]
    int e = z2 >> 8, bx = z2 & 255;
    transpose_tile(w1 + (size_t)e * D_DIM * H_DIM, w1t + (size_t)e * D_DIM * H_DIM,
                   D_DIM, H_DIM, (bx >> 6) * 256, (bx & 63) * 64, tile, threadIdx.x);
    return;
  }
  // ------- gate + convert + out bias-init -------
  int lane = threadIdx.x & 63;
  int t = z * 4 + (threadIdx.x >> 6);
  const float* xr = x + (size_t)t * D_DIM;
  unsigned short* xo = xb + (size_t)t * D_DIM;
  float acc[8];
#pragma unroll
  for (int e = 0; e < 8; e++) acc[e] = 0.f;
#pragma unroll
  for (int i = 0; i < 4; i++) {
    int d0 = lane * 4 + i * 256;
    float4 xv = *(const float4*)(xr + d0);
    ushort4 o;
    o.x = f2b(xv.x); o.y = f2b(xv.y); o.z = f2b(xv.z); o.w = f2b(xv.w);
    *(ushort4*)(xo + d0) = o;
    const float* gp = gw + (size_t)d0 * 8;
    float xs[4] = {xv.x, xv.y, xv.z, xv.w};
#pragma unroll
    for (int j = 0; j < 4; j++) {
#pragma unroll
      for (int e = 0; e < 8; e++) acc[e] += xs[j] * gp[j * 8 + e];
    }
  }
#pragma unroll
  for (int off = 32; off > 0; off >>= 1) {
#pragma unroll
    for (int e = 0; e < 8; e++) acc[e] += __shfl_xor(acc[e], off);
  }
  float lg[8];
#pragma unroll
  for (int e = 0; e < 8; e++) lg[e] = acc[e] + gb[e];
  int e0 = 0; float b0v = lg[0];
#pragma unroll
  for (int e = 1; e < 8; e++) if (lg[e] > b0v) { b0v = lg[e]; e0 = e; }
  int e1 = -1; float b1v = -1e30f;
#pragma unroll
  for (int e = 0; e < 8; e++) if (e != e0 && lg[e] > b1v) { b1v = lg[e]; e1 = e; }
  float d = __expf(b1v - b0v);
  float w0 = 1.f / (1.f + d), w1v = d / (1.f + d);
  if (lane == 0) {
    sel[t] = make_int2(e0, e1);
    wts[t] = make_float2(w0, w1v);
    atomicAdd(&meta[e0], 1);
    atomicAdd(&meta[e1], 1);
  }
  const float* ba = b2 + (size_t)e0 * D_DIM;
  const float* bb = b2 + (size_t)e1 * D_DIM;
  float* orow = out + (size_t)t * D_DIM;
#pragma unroll
  for (int k = 0; k < 4; k++) {
    int dd = lane * 4 + k * 256;
    float4 a = *(const float4*)(ba + dd);
    float4 b = *(const float4*)(bb + dd);
    float4 o;
    o.x = w0 * a.x + w1v * b.x;
    o.y = w0 * a.y + w1v * b.y;
    o.z = w0 * a.z + w1v * b.z;
    o.w = w0 * a.w + w1v * b.w;
    *(float4*)(orow + dd) = o;
  }
}

// ---------------- scatter (inline prefix from counts; cursors start at 0) ----------------
__global__ __launch_bounds__(256) void moe_scatter(const int2* __restrict__ sel,
                                                   const float2* __restrict__ wts,
                                                   int* __restrict__ meta,
                                                   int* __restrict__ token_id,
                                                   float* __restrict__ weightv) {
  int t = blockIdx.x * 256 + threadIdx.x;
  if (t >= T_TOK) return;
  int cnt[8];
#pragma unroll
  for (int e = 0; e < 8; e++) cnt[e] = meta[e];
  int2 s = sel[t];
  float2 w = wts[t];
  int o0 = 0, o1 = 0;
#pragma unroll
  for (int e = 0; e < 8; e++) {
    if (e < s.x) o0 += cnt[e];
    if (e < s.y) o1 += cnt[e];
  }
  int p0 = o0 + atomicAdd(&meta[20 + s.x], 1); token_id[p0] = t; weightv[p0] = w.x;
  int p1 = o1 + atomicAdd(&meta[20 + s.y], 1); token_id[p1] = t; weightv[p1] = w.y;
}

// Panel decode from counts: panel slot wi -> (expert e, m0, seg, ne); invalid -> e=-1.
__device__ __forceinline__ bool panel_decode(const int* __restrict__ meta, int wi,
                                             int& e, int& m0, int& seg, int& ne) {
  int acc = 0, pre = 0;
  e = -1;
#pragma unroll
  for (int k = 0; k < 8; k++) {
    int ck = meta[k];
    int nb = (ck + 127) >> 7;
    if (wi >= acc && wi < acc + nb) { e = k; m0 = (wi - acc) << 7; seg = pre; ne = ck; }
    acc += nb; pre += ck;
  }
  return e >= 0;
}

// ---------------- GEMM1' : blocks [0,TRB2) transpose w2; rest = gemm1 ----------------
// h = gelu(x@w1+b1), BK=32 2-phase, s-XOR swizzled (conflicts==0, r12).
__global__ __launch_bounds__(256, 4) void moe_gemm1(const unsigned short* __restrict__ xb,
                                                    const unsigned short* __restrict__ w1t,
                                                    const float* __restrict__ b1,
                                                    const float* __restrict__ w2,
                                                    unsigned short* __restrict__ w2t,
                                                    const int* __restrict__ meta,
                                                    const int* __restrict__ token_id,
                                                    unsigned short* __restrict__ hbuf) {
  __shared__ unsigned short SH[16640];   // max(gemm 32KiB, transpose 33.3KiB)
  int z = blockIdx.x;
  if (z < TRB2) {
    // w2 [H][D] -> w2t [D][H]
    int e = z >> 8, bx = z & 255;
    transpose_tile(w2 + (size_t)e * H_DIM * D_DIM, w2t + (size_t)e * H_DIM * D_DIM,
                   H_DIM, D_DIM, (bx >> 4) * 256, (bx & 15) * 64,
                   (unsigned short (*)[260])SH, threadIdx.x);
    return;
  }
  int b = z - TRB2;
  int c = b & 7, u = b >> 3;
  int n = u & 31, ps = u >> 5;           // NB = 32
  int e, m0, seg, ne;
  if (!panel_decode(meta, c * PPX + ps, e, m0, seg, ne)) return;
  int n0 = n * 128;
  const unsigned short* wB = w1t + (size_t)e * H_DIM * D_DIM;

  unsigned short (*As)[4096] = (unsigned short (*)[4096])SH;
  unsigned short (*Bs)[4096] = (unsigned short (*)[4096])(SH + 8192);

  int tid = threadIdx.x, lane = tid & 63, wv = tid >> 6;
  const unsigned short* aptr[2];
  const unsigned short* bptr[2];
#pragma unroll
  for (int q = 0; q < 2; q++) {
    int chunk = tid + q * 256;
    int row = chunk >> 2;
    int ko = ((chunk & 3) ^ ((chunk >> 3) & 3)) * 8;
    int gi = m0 + row; if (gi >= ne) gi = m0;
    int tok = token_id[seg + gi];
    aptr[q] = xb + (size_t)tok * D_DIM + ko;
    bptr[q] = wB + (size_t)(n0 + row) * D_DIM + ko;
  }
  auto stage = [&](int buf, int kt) {
#pragma unroll
    for (int q = 0; q < 2; q++) {
      gload_lds16(aptr[q] + kt * 32, &As[buf][(wv + 4 * q) * 512]);
      gload_lds16(bptr[q] + kt * 32, &Bs[buf][(wv + 4 * q) * 512]);
    }
  };

  f32x4 acc[4][4] = {};
  int wr = wv >> 1, wc = wv & 1;
  int sswz = ((lane >> 4) ^ ((lane >> 1) & 3)) * 8;
  int abase = (wr * 64 + (lane & 15)) * 32 + sswz;
  int bbase = (wc * 64 + (lane & 15)) * 32 + sswz;

  stage(0, 0);
  __syncthreads();
  const int nk = D_DIM / 32;
  for (int kt = 0; kt < nk; ++kt) {
    int cur = kt & 1;
    if (kt + 1 < nk) stage(cur ^ 1, kt + 1);
    bf16x8 af[4], bfr[4];
#pragma unroll
    for (int m = 0; m < 4; m++) af[m] = *(const bf16x8*)&As[cur][abase + m * 512];
#pragma unroll
    for (int nn = 0; nn < 4; nn++) bfr[nn] = *(const bf16x8*)&Bs[cur][bbase + nn * 512];
#pragma unroll
    for (int m = 0; m < 4; m++)
#pragma unroll
      for (int nn = 0; nn < 4; nn++)
        acc[m][nn] = __builtin_amdgcn_mfma_f32_16x16x32_bf16(af[m], bfr[nn], acc[m][nn], 0, 0, 0);
    __syncthreads();
  }

  int rbase = wr * 64 + (lane >> 4) * 4;
  int cbase = n0 + wc * 64 + (lane & 15);
  const float* b1e = b1 + (size_t)e * H_DIM + cbase;
  float bv[4];
#pragma unroll
  for (int nn = 0; nn < 4; nn++) bv[nn] = b1e[nn * 16];
#pragma unroll
  for (int m = 0; m < 4; m++) {
#pragma unroll
    for (int j = 0; j < 4; j++) {
      int gi = m0 + rbase + m * 16 + j;
      if (gi < ne) {
        unsigned short* hrow = hbuf + (size_t)(seg + gi) * H_DIM + cbase;
#pragma unroll
        for (int nn = 0; nn < 4; nn++) {
          float v = acc[m][nn][j] + bv[nn];
          hrow[nn * 16] = f2b(gelu_tanh(v));
        }
      }
    }
  }
}

// ---------------- GEMM2: BK=32 2-phase + split-K=2, swizzled, bias via prep init ----------
__global__ __launch_bounds__(256, 4) void moe_gemm2(const unsigned short* __restrict__ hbuf,
                                                    const unsigned short* __restrict__ w2t,
                                                    const int* __restrict__ meta,
                                                    const int* __restrict__ token_id,
                                                    const float* __restrict__ weightv,
                                                    float* __restrict__ out) {
  int b = blockIdx.x;
  int c = b & 7, u = b >> 3;
  int n = u & 7, ks = (u >> 3) & 1, ps = u >> 4;   // NB = 8, KS = 2
  int e, m0, seg, ne;
  if (!panel_decode(meta, c * PPX + ps, e, m0, seg, ne)) return;
  int n0 = n * 128;
  int kbase = ks * 2048;
  const unsigned short* wB = w2t + (size_t)e * D_DIM * H_DIM;

  __shared__ unsigned short As[2][4096];
  __shared__ unsigned short Bs[2][4096];

  int tid = threadIdx.x, lane = tid & 63, wv = tid >> 6;
  const unsigned short* aptr[2];
  const unsigned short* bptr[2];
#pragma unroll
  for (int q = 0; q < 2; q++) {
    int chunk = tid + q * 256;
    int row = chunk >> 2;
    int ko = ((chunk & 3) ^ ((chunk >> 3) & 3)) * 8;
    int gi = m0 + row; if (gi >= ne) gi = m0;
    aptr[q] = hbuf + (size_t)(seg + gi) * H_DIM + kbase + ko;
    bptr[q] = wB + (size_t)(n0 + row) * H_DIM + kbase + ko;
  }
  auto stage = [&](int buf, int kt) {
#pragma unroll
    for (int q = 0; q < 2; q++) {
      gload_lds16(aptr[q] + kt * 32, &As[buf][(wv + 4 * q) * 512]);
      gload_lds16(bptr[q] + kt * 32, &Bs[buf][(wv + 4 * q) * 512]);
    }
  };

  f32x4 acc[4][4] = {};
  int wr = wv >> 1, wc = wv & 1;
  int sswz = ((lane >> 4) ^ ((lane >> 1) & 3)) * 8;
  int abase = (wr * 64 + (lane & 15)) * 32 + sswz;
  int bbase = (wc * 64 + (lane & 15)) * 32 + sswz;

  stage(0, 0);
  __syncthreads();
  const int nk = 2048 / 32;   // 64 K-tiles per half
  for (int kt = 0; kt < nk; ++kt) {
    int cur = kt & 1;
    if (kt + 1 < nk) stage(cur ^ 1, kt + 1);
    bf16x8 af[4], bfr[4];
#pragma unroll
    for (int m = 0; m < 4; m++) af[m] = *(const bf16x8*)&As[cur][abase + m * 512];
#pragma unroll
    for (int nn = 0; nn < 4; nn++) bfr[nn] = *(const bf16x8*)&Bs[cur][bbase + nn * 512];
#pragma unroll
    for (int m = 0; m < 4; m++)
#pragma unroll
      for (int nn = 0; nn < 4; nn++)
        acc[m][nn] = __builtin_amdgcn_mfma_f32_16x16x32_bf16(af[m], bfr[nn], acc[m][nn], 0, 0, 0);
    __syncthreads();
  }

  int rbase = wr * 64 + (lane >> 4) * 4;
  int cbase = n0 + wc * 64 + (lane & 15);
#pragma unroll
  for (int m = 0; m < 4; m++) {
#pragma unroll
    for (int j = 0; j < 4; j++) {
      int gi = m0 + rbase + m * 16 + j;
      if (gi < ne) {
        int p = seg + gi;
        int tok = token_id[p];
        float wt = weightv[p];
        float* orow = out + (size_t)tok * D_DIM + cbase;
#pragma unroll
        for (int nn = 0; nn < 4; nn++)
          atomicAdd(&orow[nn * 16], wt * acc[m][nn][j]);
      }
    }
  }
}

extern "C" void kernel_launch(void* const* d_in, const int* in_sizes, int n_in,
                              void* d_out, int out_size, void* d_ws, size_t ws_size,
                              hipStream_t stream) {
  const float* x      = (const float*)d_in[0];
  const float* gate_w = (const float*)d_in[1];
  const float* gate_b = (const float*)d_in[2];
  const float* w1     = (const float*)d_in[3];
  const float* b1     = (const float*)d_in[4];
  const float* w2     = (const float*)d_in[5];
  const float* b2     = (const float*)d_in[6];
  float* out = (float*)d_out;

  uint8_t* ws = (uint8_t*)d_ws;
  unsigned short* hbuf = (unsigned short*)(ws);                 // 128 MiB
  unsigned short* xb   = (unsigned short*)(ws + 134217728ull);  // 16 MiB
  unsigned short* w1t  = (unsigned short*)(ws + 150994944ull);  // 64 MiB
  unsigned short* w2t  = (unsigned short*)(ws + 218103808ull);  // 64 MiB
  int*    token_id = (int*)  (ws + 285212672ull);               // 64 KiB
  float*  weightv  = (float*)(ws + 285278208ull);               // 64 KiB
  float2* wts      = (float2*)(ws + 285343744ull);              // 64 KiB
  int2*   sel      = (int2*) (ws + 285409280ull);               // 64 KiB
  int*    meta     = (int*)  (ws + 285474816ull);               // 512 B

  hipMemsetAsync(meta, 0, 128, stream);

  moe_prep<<<dim3(GATEB + TRB1), 256, 0, stream>>>(
      x, gate_w, gate_b, w1, b2, xb, w1t, sel, wts, meta, out);
  moe_scatter<<<dim3(T_TOK / 256), 256, 0, stream>>>(sel, wts, meta, token_id, weightv);

  moe_gemm1<<<dim3(TRB2 + NPAD * 32), 256, 0, stream>>>(
      xb, w1t, b1, w2, w2t, meta, token_id, hbuf);
  moe_gemm2<<<dim3(NPAD * 16), 256, 0, stream>>>(hbuf, w2t, meta, token_id, weightv, out);
}

// Round 17
// 789.055 us; speedup vs baseline: 1.0307x; 1.0054x over previous
//
#include <hip/hip_runtime.h>
#include <hip/hip_bf16.h>
#include <stdint.h>

#define T_TOK 8192
#define D_DIM 1024
#define E_NUM 8
#define H_DIM 4096
#define NPAD 144          // padded panel count, multiple of 8 (max panels = 135)
#define PPX (NPAD / 8)    // panels per XCD chunk = 18
#define GATEB 2048        // gate blocks (4 tokens each)
#define TRB1 2048         // w1 transpose blocks (in prep)
#define TRB2 2048         // w2 transpose blocks (in gemm1')

typedef short bf16x8 __attribute__((ext_vector_type(8)));
typedef float f32x4 __attribute__((ext_vector_type(4)));
typedef unsigned short usv8 __attribute__((ext_vector_type(8)));

#define AS1 __attribute__((address_space(1)))
#define AS3 __attribute__((address_space(3)))

__device__ __forceinline__ unsigned short f2b(float f) {
  union { float f; uint32_t u; } v; v.f = f;
  uint32_t r = (v.u + 0x7fffu + ((v.u >> 16) & 1u)) >> 16;
  return (unsigned short)r;
}

__device__ __forceinline__ float gelu_tanh(float x) {
  float u = 0.7978845608028654f * (x + 0.044715f * x * x * x);
  u = fminf(fmaxf(u, -15.f), 15.f);
  float e = __expf(2.f * u);
  float t = (e - 1.f) / (e + 1.f);
  return 0.5f * x * (1.f + t);
}

__device__ __forceinline__ void gload_lds16(const void* g, void* l) {
  __builtin_amdgcn_global_load_lds((const AS1 uint32_t*)g, (AS3 uint32_t*)l, 16, 0, 0);
}

// 256x64 fp32->bf16 transpose tile with 512B-coalesced writes via LDS (r15-verified).
__device__ __forceinline__ void transpose_tile(const float* __restrict__ in,
                                               unsigned short* __restrict__ outp,
                                               int R, int C, int r0, int c0,
                                               unsigned short (*tile)[260], int t) {
  int sc = (t & 15) * 4;
  int srb = (t >> 4) * 4;
#pragma unroll
  for (int it = 0; it < 4; ++it) {
    int sr = srb + it * 64;
    float4 v0 = *(const float4*)(in + (size_t)(r0 + sr + 0) * C + c0 + sc);
    float4 v1 = *(const float4*)(in + (size_t)(r0 + sr + 1) * C + c0 + sc);
    float4 v2 = *(const float4*)(in + (size_t)(r0 + sr + 2) * C + c0 + sc);
    float4 v3 = *(const float4*)(in + (size_t)(r0 + sr + 3) * C + c0 + sc);
    ushort4 o;
    o.x = f2b(v0.x); o.y = f2b(v1.x); o.z = f2b(v2.x); o.w = f2b(v3.x);
    *(ushort4*)&tile[sc + 0][sr] = o;
    o.x = f2b(v0.y); o.y = f2b(v1.y); o.z = f2b(v2.y); o.w = f2b(v3.y);
    *(ushort4*)&tile[sc + 1][sr] = o;
    o.x = f2b(v0.z); o.y = f2b(v1.z); o.z = f2b(v2.z); o.w = f2b(v3.z);
    *(ushort4*)&tile[sc + 2][sr] = o;
    o.x = f2b(v0.w); o.y = f2b(v1.w); o.z = f2b(v2.w); o.w = f2b(v3.w);
    *(ushort4*)&tile[sc + 3][sr] = o;
  }
  __syncthreads();
  int wv = t >> 6, lane = t & 63;
  int rowHalf = lane >> 5, el = (lane & 31) * 8;
#pragma unroll
  for (int it = 0; it < 8; ++it) {
    int orow = wv * 16 + it * 2 + rowHalf;
    usv8 o = *(const usv8*)&tile[orow][el];
    *(usv8*)(outp + (size_t)(c0 + orow) * R + r0 + el) = o;
  }
}

// ---------------- prep: gate (+x->bf16 +out bias-init) + w1 transpose ----------------
// Gate blocks stage gate_w TRANSPOSED in LDS first (the [D][E] layout's stride-32 gather
// was a 64-cache-line/load pathology -- r16 diagnosis).
__global__ __launch_bounds__(256) void moe_prep(const float* __restrict__ x,
                                                const float* __restrict__ gw,
                                                const float* __restrict__ gb,
                                                const float* __restrict__ w1,
                                                const float* __restrict__ b2,
                                                unsigned short* __restrict__ xb,
                                                unsigned short* __restrict__ w1t,
                                                int2* __restrict__ sel,
                                                float2* __restrict__ wts,
                                                int* __restrict__ meta,
                                                float* __restrict__ out) {
  __shared__ __align__(16) unsigned short SH[64 * 260];   // 33.3 KiB (transpose tile / gwT)
  int z = blockIdx.x;
  if (z >= GATEB) {
    int z2 = z - GATEB;            // 0..2047: w1 [D][H] -> w1t [H][D]
    int e = z2 >> 8, bx = z2 & 255;
    transpose_tile(w1 + (size_t)e * D_DIM * H_DIM, w1t + (size_t)e * D_DIM * H_DIM,
                   D_DIM, H_DIM, (bx >> 6) * 256, (bx & 63) * 64,
                   (unsigned short (*)[260])SH, threadIdx.x);
    return;
  }
  // ------- stage gwT[e][d] in LDS (coalesced global read, scattered 4B LDS writes) -------
  float* gwT = (float*)SH;   // [8][1024] f32 = 32 KiB
#pragma unroll
  for (int it = 0; it < 8; ++it) {
    int g = it * 1024 + threadIdx.x * 4;     // g multiple of 4 -> g&7 in {0,4}
    float4 v = *(const float4*)(gw + g);
    int d = g >> 3, ep = g & 7;
    gwT[(ep + 0) * 1024 + d] = v.x;
    gwT[(ep + 1) * 1024 + d] = v.y;
    gwT[(ep + 2) * 1024 + d] = v.z;
    gwT[(ep + 3) * 1024 + d] = v.w;
  }
  __syncthreads();
  // ------- gate + convert + out bias-init -------
  int lane = threadIdx.x & 63;
  int t = z * 4 + (threadIdx.x >> 6);
  const float* xr = x + (size_t)t * D_DIM;
  unsigned short* xo = xb + (size_t)t * D_DIM;
  float acc[8];
#pragma unroll
  for (int e = 0; e < 8; e++) acc[e] = 0.f;
#pragma unroll
  for (int i = 0; i < 4; i++) {
    int d0 = lane * 4 + i * 256;
    float4 xv = *(const float4*)(xr + d0);
    ushort4 o;
    o.x = f2b(xv.x); o.y = f2b(xv.y); o.z = f2b(xv.z); o.w = f2b(xv.w);
    *(ushort4*)(xo + d0) = o;
#pragma unroll
    for (int e = 0; e < 8; e++) {
      float4 gv = *(const float4*)(gwT + e * 1024 + d0);   // ds_read_b128, conflict-free
      acc[e] += xv.x * gv.x + xv.y * gv.y + xv.z * gv.z + xv.w * gv.w;
    }
  }
#pragma unroll
  for (int off = 32; off > 0; off >>= 1) {
#pragma unroll
    for (int e = 0; e < 8; e++) acc[e] += __shfl_xor(acc[e], off);
  }
  float lg[8];
#pragma unroll
  for (int e = 0; e < 8; e++) lg[e] = acc[e] + gb[e];
  int e0 = 0; float b0v = lg[0];
#pragma unroll
  for (int e = 1; e < 8; e++) if (lg[e] > b0v) { b0v = lg[e]; e0 = e; }
  int e1 = -1; float b1v = -1e30f;
#pragma unroll
  for (int e = 0; e < 8; e++) if (e != e0 && lg[e] > b1v) { b1v = lg[e]; e1 = e; }
  float d = __expf(b1v - b0v);
  float w0 = 1.f / (1.f + d), w1v = d / (1.f + d);
  if (lane == 0) {
    sel[t] = make_int2(e0, e1);
    wts[t] = make_float2(w0, w1v);
    atomicAdd(&meta[e0], 1);
    atomicAdd(&meta[e1], 1);
  }
  const float* ba = b2 + (size_t)e0 * D_DIM;
  const float* bb = b2 + (size_t)e1 * D_DIM;
  float* orow = out + (size_t)t * D_DIM;
#pragma unroll
  for (int k = 0; k < 4; k++) {
    int dd = lane * 4 + k * 256;
    float4 a = *(const float4*)(ba + dd);
    float4 b = *(const float4*)(bb + dd);
    float4 o;
    o.x = w0 * a.x + w1v * b.x;
    o.y = w0 * a.y + w1v * b.y;
    o.z = w0 * a.z + w1v * b.z;
    o.w = w0 * a.w + w1v * b.w;
    *(float4*)(orow + dd) = o;
  }
}

// ---------------- scatter (inline prefix from counts; cursors start at 0) ----------------
__global__ __launch_bounds__(256) void moe_scatter(const int2* __restrict__ sel,
                                                   const float2* __restrict__ wts,
                                                   int* __restrict__ meta,
                                                   int* __restrict__ token_id,
                                                   float* __restrict__ weightv) {
  int t = blockIdx.x * 256 + threadIdx.x;
  if (t >= T_TOK) return;
  int cnt[8];
#pragma unroll
  for (int e = 0; e < 8; e++) cnt[e] = meta[e];
  int2 s = sel[t];
  float2 w = wts[t];
  int o0 = 0, o1 = 0;
#pragma unroll
  for (int e = 0; e < 8; e++) {
    if (e < s.x) o0 += cnt[e];
    if (e < s.y) o1 += cnt[e];
  }
  int p0 = o0 + atomicAdd(&meta[20 + s.x], 1); token_id[p0] = t; weightv[p0] = w.x;
  int p1 = o1 + atomicAdd(&meta[20 + s.y], 1); token_id[p1] = t; weightv[p1] = w.y;
}

// Panel decode from counts: panel slot wi -> (expert e, m0, seg, ne); invalid -> e=-1.
__device__ __forceinline__ bool panel_decode(const int* __restrict__ meta, int wi,
                                             int& e, int& m0, int& seg, int& ne) {
  int acc = 0, pre = 0;
  e = -1;
#pragma unroll
  for (int k = 0; k < 8; k++) {
    int ck = meta[k];
    int nb = (ck + 127) >> 7;
    if (wi >= acc && wi < acc + nb) { e = k; m0 = (wi - acc) << 7; seg = pre; ne = ck; }
    acc += nb; pre += ck;
  }
  return e >= 0;
}

// ---------------- GEMM1' : blocks [0,TRB2) transpose w2; rest = gemm1 ----------------
// h = gelu(x@w1+b1), BK=32 2-phase, s-XOR swizzled (conflicts==0, r12).
__global__ __launch_bounds__(256, 4) void moe_gemm1(const unsigned short* __restrict__ xb,
                                                    const unsigned short* __restrict__ w1t,
                                                    const float* __restrict__ b1,
                                                    const float* __restrict__ w2,
                                                    unsigned short* __restrict__ w2t,
                                                    const int* __restrict__ meta,
                                                    const int* __restrict__ token_id,
                                                    unsigned short* __restrict__ hbuf) {
  __shared__ __align__(16) unsigned short SH[16640];   // max(gemm 32KiB, transpose 33.3KiB)
  int z = blockIdx.x;
  if (z < TRB2) {
    // w2 [H][D] -> w2t [D][H]
    int e = z >> 8, bx = z & 255;
    transpose_tile(w2 + (size_t)e * H_DIM * D_DIM, w2t + (size_t)e * H_DIM * D_DIM,
                   H_DIM, D_DIM, (bx >> 4) * 256, (bx & 15) * 64,
                   (unsigned short (*)[260])SH, threadIdx.x);
    return;
  }
  int b = z - TRB2;
  int c = b & 7, u = b >> 3;
  int n = u & 31, ps = u >> 5;           // NB = 32
  int e, m0, seg, ne;
  if (!panel_decode(meta, c * PPX + ps, e, m0, seg, ne)) return;
  int n0 = n * 128;
  const unsigned short* wB = w1t + (size_t)e * H_DIM * D_DIM;

  unsigned short (*As)[4096] = (unsigned short (*)[4096])SH;
  unsigned short (*Bs)[4096] = (unsigned short (*)[4096])(SH + 8192);

  int tid = threadIdx.x, lane = tid & 63, wv = tid >> 6;
  const unsigned short* aptr[2];
  const unsigned short* bptr[2];
#pragma unroll
  for (int q = 0; q < 2; q++) {
    int chunk = tid + q * 256;
    int row = chunk >> 2;
    int ko = ((chunk & 3) ^ ((chunk >> 3) & 3)) * 8;
    int gi = m0 + row; if (gi >= ne) gi = m0;
    int tok = token_id[seg + gi];
    aptr[q] = xb + (size_t)tok * D_DIM + ko;
    bptr[q] = wB + (size_t)(n0 + row) * D_DIM + ko;
  }
  auto stage = [&](int buf, int kt) {
#pragma unroll
    for (int q = 0; q < 2; q++) {
      gload_lds16(aptr[q] + kt * 32, &As[buf][(wv + 4 * q) * 512]);
      gload_lds16(bptr[q] + kt * 32, &Bs[buf][(wv + 4 * q) * 512]);
    }
  };

  f32x4 acc[4][4] = {};
  int wr = wv >> 1, wc = wv & 1;
  int sswz = ((lane >> 4) ^ ((lane >> 1) & 3)) * 8;
  int abase = (wr * 64 + (lane & 15)) * 32 + sswz;
  int bbase = (wc * 64 + (lane & 15)) * 32 + sswz;

  stage(0, 0);
  __syncthreads();
  const int nk = D_DIM / 32;
  for (int kt = 0; kt < nk; ++kt) {
    int cur = kt & 1;
    if (kt + 1 < nk) stage(cur ^ 1, kt + 1);
    bf16x8 af[4], bfr[4];
#pragma unroll
    for (int m = 0; m < 4; m++) af[m] = *(const bf16x8*)&As[cur][abase + m * 512];
#pragma unroll
    for (int nn = 0; nn < 4; nn++) bfr[nn] = *(const bf16x8*)&Bs[cur][bbase + nn * 512];
#pragma unroll
    for (int m = 0; m < 4; m++)
#pragma unroll
      for (int nn = 0; nn < 4; nn++)
        acc[m][nn] = __builtin_amdgcn_mfma_f32_16x16x32_bf16(af[m], bfr[nn], acc[m][nn], 0, 0, 0);
    __syncthreads();
  }

  int rbase = wr * 64 + (lane >> 4) * 4;
  int cbase = n0 + wc * 64 + (lane & 15);
  const float* b1e = b1 + (size_t)e * H_DIM + cbase;
  float bv[4];
#pragma unroll
  for (int nn = 0; nn < 4; nn++) bv[nn] = b1e[nn * 16];
#pragma unroll
  for (int m = 0; m < 4; m++) {
#pragma unroll
    for (int j = 0; j < 4; j++) {
      int gi = m0 + rbase + m * 16 + j;
      if (gi < ne) {
        unsigned short* hrow = hbuf + (size_t)(seg + gi) * H_DIM + cbase;
#pragma unroll
        for (int nn = 0; nn < 4; nn++) {
          float v = acc[m][nn][j] + bv[nn];
          hrow[nn * 16] = f2b(gelu_tanh(v));
        }
      }
    }
  }
}

// ---------------- GEMM2: BK=32 2-phase + split-K=2, swizzled, bias via prep init ----------
__global__ __launch_bounds__(256, 4) void moe_gemm2(const unsigned short* __restrict__ hbuf,
                                                    const unsigned short* __restrict__ w2t,
                                                    const int* __restrict__ meta,
                                                    const int* __restrict__ token_id,
                                                    const float* __restrict__ weightv,
                                                    float* __restrict__ out) {
  int b = blockIdx.x;
  int c = b & 7, u = b >> 3;
  int n = u & 7, ks = (u >> 3) & 1, ps = u >> 4;   // NB = 8, KS = 2
  int e, m0, seg, ne;
  if (!panel_decode(meta, c * PPX + ps, e, m0, seg, ne)) return;
  int n0 = n * 128;
  int kbase = ks * 2048;
  const unsigned short* wB = w2t + (size_t)e * D_DIM * H_DIM;

  __shared__ unsigned short As[2][4096];
  __shared__ unsigned short Bs[2][4096];

  int tid = threadIdx.x, lane = tid & 63, wv = tid >> 6;
  const unsigned short* aptr[2];
  const unsigned short* bptr[2];
#pragma unroll
  for (int q = 0; q < 2; q++) {
    int chunk = tid + q * 256;
    int row = chunk >> 2;
    int ko = ((chunk & 3) ^ ((chunk >> 3) & 3)) * 8;
    int gi = m0 + row; if (gi >= ne) gi = m0;
    aptr[q] = hbuf + (size_t)(seg + gi) * H_DIM + kbase + ko;
    bptr[q] = wB + (size_t)(n0 + row) * H_DIM + kbase + ko;
  }
  auto stage = [&](int buf, int kt) {
#pragma unroll
    for (int q = 0; q < 2; q++) {
      gload_lds16(aptr[q] + kt * 32, &As[buf][(wv + 4 * q) * 512]);
      gload_lds16(bptr[q] + kt * 32, &Bs[buf][(wv + 4 * q) * 512]);
    }
  };

  f32x4 acc[4][4] = {};
  int wr = wv >> 1, wc = wv & 1;
  int sswz = ((lane >> 4) ^ ((lane >> 1) & 3)) * 8;
  int abase = (wr * 64 + (lane & 15)) * 32 + sswz;
  int bbase = (wc * 64 + (lane & 15)) * 32 + sswz;

  stage(0, 0);
  __syncthreads();
  const int nk = 2048 / 32;   // 64 K-tiles per half
  for (int kt = 0; kt < nk; ++kt) {
    int cur = kt & 1;
    if (kt + 1 < nk) stage(cur ^ 1, kt + 1);
    bf16x8 af[4], bfr[4];
#pragma unroll
    for (int m = 0; m < 4; m++) af[m] = *(const bf16x8*)&As[cur][abase + m * 512];
#pragma unroll
    for (int nn = 0; nn < 4; nn++) bfr[nn] = *(const bf16x8*)&Bs[cur][bbase + nn * 512];
#pragma unroll
    for (int m = 0; m < 4; m++)
#pragma unroll
      for (int nn = 0; nn < 4; nn++)
        acc[m][nn] = __builtin_amdgcn_mfma_f32_16x16x32_bf16(af[m], bfr[nn], acc[m][nn], 0, 0, 0);
    __syncthreads();
  }

  int rbase = wr * 64 + (lane >> 4) * 4;
  int cbase = n0 + wc * 64 + (lane & 15);
#pragma unroll
  for (int m = 0; m < 4; m++) {
#pragma unroll
    for (int j = 0; j < 4; j++) {
      int gi = m0 + rbase + m * 16 + j;
      if (gi < ne) {
        int p = seg + gi;
        int tok = token_id[p];
        float wt = weightv[p];
        float* orow = out + (size_t)tok * D_DIM + cbase;
#pragma unroll
        for (int nn = 0; nn < 4; nn++)
          atomicAdd(&orow[nn * 16], wt * acc[m][nn][j]);
      }
    }
  }
}

extern "C" void kernel_launch(void* const* d_in, const int* in_sizes, int n_in,
                              void* d_out, int out_size, void* d_ws, size_t ws_size,
                              hipStream_t stream) {
  const float* x      = (const float*)d_in[0];
  const float* gate_w = (const float*)d_in[1];
  const float* gate_b = (const float*)d_in[2];
  const float* w1     = (const float*)d_in[3];
  const float* b1     = (const float*)d_in[4];
  const float* w2     = (const float*)d_in[5];
  const float* b2     = (const float*)d_in[6];
  float* out = (float*)d_out;

  uint8_t* ws = (uint8_t*)d_ws;
  unsigned short* hbuf = (unsigned short*)(ws);                 // 128 MiB
  unsigned short* xb   = (unsigned short*)(ws + 134217728ull);  // 16 MiB
  unsigned short* w1t  = (unsigned short*)(ws + 150994944ull);  // 64 MiB
  unsigned short* w2t  = (unsigned short*)(ws + 218103808ull);  // 64 MiB
  int*    token_id = (int*)  (ws + 285212672ull);               // 64 KiB
  float*  weightv  = (float*)(ws + 285278208ull);               // 64 KiB
  float2* wts      = (float2*)(ws + 285343744ull);              // 64 KiB
  int2*   sel      = (int2*) (ws + 285409280ull);               // 64 KiB
  int*    meta     = (int*)  (ws + 285474816ull);               // 512 B

  hipMemsetAsync(meta, 0, 128, stream);

  moe_prep<<<dim3(GATEB + TRB1), 256, 0, stream>>>(
      x, gate_w, gate_b, w1, b2, xb, w1t, sel, wts, meta, out);
  moe_scatter<<<dim3(T_TOK / 256), 256, 0, stream>>>(sel, wts, meta, token_id, weightv);

  moe_gemm1<<<dim3(TRB2 + NPAD * 32), 256, 0, stream>>>(
      xb, w1t, b1, w2, w2t, meta, token_id, hbuf);
  moe_gemm2<<<dim3(NPAD * 16), 256, 0, stream>>>(hbuf, w2t, meta, token_id, weightv, out);
}